// Round 6
// baseline (171.371 us; speedup 1.0000x reference)
//
#include <hip/hip_runtime.h>
#include <math.h>

#define BATCH   262144
#define CLUSTER 100

// Analytic Lorentz boost matrix B = I - (g*mag)*nK + (g-1)*nK^2:
//   B[0][0]     = g
//   B[0][j+1]   = B[j+1][0] = -(g*mag)*n_j
//   B[i+1][j+1] = delta_ij + (g-1)*n_i*n_j
__device__ inline void boost_mat(float bx, float by, float bz, float B[4][4]) {
    float m2  = bx * bx + by * by + bz * bz;
    float mag = sqrtf(m2);
    float nx = bx / mag, ny = by / mag, nz = bz / mag;
    float g  = 1.0f / sqrtf(1.0f - mag * mag);
    float gm = g * mag;
    float gm1 = g - 1.0f;
    float n[3] = {nx, ny, nz};
    B[0][0] = 1.0f + gm1 * (nx * nx + ny * ny + nz * nz);
    for (int j = 0; j < 3; ++j) {
        B[0][j + 1] = -gm * n[j];
        B[j + 1][0] = -gm * n[j];
    }
    for (int i = 0; i < 3; ++i)
        for (int j = 0; j < 3; ++j)
            B[i + 1][j + 1] = ((i == j) ? 1.0f : 0.0f) + gm1 * n[i] * n[j];
}

#define DOT4(mm, vv) ((mm).x*(vv).x + (mm).y*(vv).y + (mm).z*(vv).z + (mm).w*(vv).w)

// out[b][a] = sum_c sum_d M[c][a][d] * T[b][c][d],  M_c = BiM @ (W_c * BoM_c)
//
// HBM side: each wave stages its 8 rows (12,800B) with 13 fully-LINEAR
// wave-loads (1024B contiguous, 128B-aligned each) -> identical pattern to the
// 6.3 TB/s float4-copy ceiling. Row/cluster indexing happens on the LDS side.
// LDS side: 16-lane group g owns local rows {2g, 2g+1}; lane q reads clusters
// c = 16t+q. All ds_read_b128 are bank-uniform (8 words/bank); M-reads are
// 4-way same-address broadcasts. sM is SoA to spread banks.
__global__ __launch_bounds__(256) void lorentz_staged_kernel(
        const float4* __restrict__ T4,
        const float*  __restrict__ Bo,
        const float*  __restrict__ Bi,
        const float*  __restrict__ W,
        float4* __restrict__ out4) {
    __shared__ float  sMr[4][CLUSTER * 4];   // 6.4 KB, SoA: sMr[a][c*4+d]
    __shared__ float4 sT[4][800];            // 51.2 KB: 4 waves x 8 rows x 100

    int tid  = threadIdx.x;
    int w    = tid >> 6;
    int lane = tid & 63;

    long long waveRow = (long long)blockIdx.x * 32 + w * 8;
    const float4* src = T4 + waveRow * CLUSTER;

    // --- 1. issue ALL staging loads first (in flight during the M build) ---
    float4 r[13];
    #pragma unroll
    for (int s = 0; s < 12; ++s)
        r[s] = src[s * 64 + lane];
    if (lane < 32)
        r[12] = src[768 + lane];

    // --- 2. build all 100 M_c matrices (VALU work hidden under HBM latency) ---
    if (tid < CLUSTER) {
        float BiM[4][4], BoM[4][4];
        boost_mat(Bi[0], Bi[1], Bi[2], BiM);
        boost_mat(Bo[tid * 3 + 0], Bo[tid * 3 + 1], Bo[tid * 3 + 2], BoM);
        float wt = W[tid];
        for (int a = 0; a < 4; ++a)
            for (int d = 0; d < 4; ++d) {
                float s = 0.0f;
                for (int e = 0; e < 4; ++e)
                    s += BiM[a][e] * (wt * BoM[e][d]);
                sMr[a][tid * 4 + d] = s;
            }
    }

    // --- 3. write staged tile to LDS (lane-linear, bank-uniform) ---
    #pragma unroll
    for (int s = 0; s < 12; ++s)
        sT[w][s * 64 + lane] = r[s];
    if (lane < 32)
        sT[w][768 + lane] = r[12];

    __syncthreads();

    // --- 4. consume from LDS ---
    int q = lane & 15;      // cluster phase within 16-lane group
    int g = lane >> 4;      // group 0..3, owns local rows 2g, 2g+1
    const float4* row0 = &sT[w][(2 * g)     * CLUSTER];
    const float4* row1 = &sT[w][(2 * g + 1) * CLUSTER];

    float4 a0 = {0.f, 0.f, 0.f, 0.f};
    float4 a1 = a0;

    #define ACCSTEP(c)                                                        \
    {                                                                         \
        float4 v0 = row0[c], v1 = row1[c];                                    \
        float4 m0 = *(const float4*)&sMr[0][(c) * 4];                         \
        float4 m1 = *(const float4*)&sMr[1][(c) * 4];                         \
        float4 m2 = *(const float4*)&sMr[2][(c) * 4];                         \
        float4 m3 = *(const float4*)&sMr[3][(c) * 4];                         \
        a0.x += DOT4(m0, v0); a0.y += DOT4(m1, v0); a0.z += DOT4(m2, v0); a0.w += DOT4(m3, v0); \
        a1.x += DOT4(m0, v1); a1.y += DOT4(m1, v1); a1.z += DOT4(m2, v1); a1.w += DOT4(m3, v1); \
    }

    #pragma unroll
    for (int t = 0; t < 6; ++t) {
        int c = 16 * t + q;
        ACCSTEP(c)
    }
    if (q < 4) {
        ACCSTEP(96 + q)     // tail clusters 96..99
    }
    #undef ACCSTEP

    // --- 5. butterfly reduce across the 16-lane group ---
    #define RED(f) f += __shfl_xor(f, 1); f += __shfl_xor(f, 2); \
                   f += __shfl_xor(f, 4); f += __shfl_xor(f, 8);
    RED(a0.x) RED(a0.y) RED(a0.z) RED(a0.w)
    RED(a1.x) RED(a1.y) RED(a1.z) RED(a1.w)
    #undef RED

    // --- 6. store: 8 lanes per wave write 128B contiguous ---
    if (q == 0) out4[waveRow + 2 * g]     = a0;
    if (q == 1) out4[waveRow + 2 * g + 1] = a1;
}

extern "C" void kernel_launch(void* const* d_in, const int* in_sizes, int n_in,
                              void* d_out, int out_size, void* d_ws, size_t ws_size,
                              hipStream_t stream) {
    const float4* T4 = (const float4*)d_in[0];
    const float*  Bo = (const float*)d_in[1];
    const float*  Bi = (const float*)d_in[2];
    const float*  W  = (const float*)d_in[3];
    // d_in[4] = K_mats (folded into analytic boost formula)

    float4* out4 = (float4*)d_out;

    int blocks = BATCH / 32;   // 32 rows per block (4 waves x 8 rows)
    lorentz_staged_kernel<<<blocks, 256, 0, stream>>>(T4, Bo, Bi, W, out4);
}

// Round 7
// 81.680 us; speedup vs baseline: 2.0981x; 2.0981x over previous
//
#include <hip/hip_runtime.h>
#include <math.h>

#define BATCH   262144
#define CLUSTER 100

// Analytic Lorentz boost matrix B = I - (g*mag)*nK + (g-1)*nK^2:
//   B[0][0]     = g
//   B[0][j+1]   = B[j+1][0] = -(g*mag)*n_j
//   B[i+1][j+1] = delta_ij + (g-1)*n_i*n_j
__device__ inline void boost_mat(float bx, float by, float bz, float B[4][4]) {
    float m2  = bx * bx + by * by + bz * bz;
    float mag = sqrtf(m2);
    float nx = bx / mag, ny = by / mag, nz = bz / mag;
    float g  = 1.0f / sqrtf(1.0f - mag * mag);
    float gm = g * mag;
    float gm1 = g - 1.0f;
    float n[3] = {nx, ny, nz};
    B[0][0] = 1.0f + gm1 * (nx * nx + ny * ny + nz * nz);
    for (int j = 0; j < 3; ++j) {
        B[0][j + 1] = -gm * n[j];
        B[j + 1][0] = -gm * n[j];
    }
    for (int i = 0; i < 3; ++i)
        for (int j = 0; j < 3; ++j)
            B[i + 1][j + 1] = ((i == j) ? 1.0f : 0.0f) + gm1 * n[i] * n[j];
}

#define DOT4(mm, vv) ((mm).x*(vv).x + (mm).y*(vv).y + (mm).z*(vv).z + (mm).w*(vv).w)

// out[b][a] = sum_c sum_d M[c][a][d] * T[b][c][d],  M_c = BiM @ (W_c * BoM_c)
//
// Super-row = 2 consecutive rows = 200 float4 = 3200B == 0 mod 128: perfectly
// cache-line aligned. 32-lane group walks 2 super-rows linearly (lane q reads
// index 32t+q, t=0..6): every wave-load is 2 x 512B dense aligned segments --
// the same pattern as the 6.3 TB/s copy ceiling. No LDS staging of T; direct
// global->register stream like R2. Row boundary (index 100) falls at
// compile-time (t,q): only step t=3 routes per-lane.
__global__ __launch_bounds__(256) void lorentz_pair_kernel(
        const float4* __restrict__ T4,
        const float*  __restrict__ Bo,
        const float*  __restrict__ Bi,
        const float*  __restrict__ W,
        float4* __restrict__ out4) {
    __shared__ float sMr[4][CLUSTER * 4];   // SoA: sMr[a][c*4+d], 6.4 KB

    int tid  = threadIdx.x;
    int w    = tid >> 6;
    int lane = tid & 63;
    int q = lane & 31;      // position in 32-lane group
    int h = lane >> 5;      // group 0..1; owns super-rows sp0, sp0+1

    long long spBase = (long long)blockIdx.x * 16 + w * 4;  // 16 super-rows/block
    long long sp0    = spBase + 2 * h;
    const float4* S0 = T4 + sp0 * 200;       // super-row 0 (rows 2sp0, 2sp0+1)
    const float4* S1 = S0 + 200;             // super-row 1 (rows 2sp0+2, 2sp0+3)

    // t=0 preload: in flight during the M build
    float4 v0 = S0[q];
    float4 v1 = S1[q];

    // build all 100 M_c matrices in-block
    if (tid < CLUSTER) {
        float BiM[4][4], BoM[4][4];
        boost_mat(Bi[0], Bi[1], Bi[2], BiM);
        boost_mat(Bo[tid * 3 + 0], Bo[tid * 3 + 1], Bo[tid * 3 + 2], BoM);
        float wt = W[tid];
        for (int a = 0; a < 4; ++a)
            for (int d = 0; d < 4; ++d) {
                float s = 0.0f;
                for (int e = 0; e < 4; ++e)
                    s += BiM[a][e] * (wt * BoM[e][d]);
                sMr[a][tid * 4 + d] = s;
            }
    }
    __syncthreads();

    // accumulators: a0,a1 = rows 2sp0, 2sp0+1 (from S0); a2,a3 = rows 2sp0+2,+3
    float4 a0 = {0.f, 0.f, 0.f, 0.f};
    float4 a1 = a0, a2 = a0, a3 = a0;

    #define DOTS(c, v, A)                                                     \
    {                                                                         \
        float4 m0 = *(const float4*)&sMr[0][(c) * 4];                         \
        float4 m1 = *(const float4*)&sMr[1][(c) * 4];                         \
        float4 m2 = *(const float4*)&sMr[2][(c) * 4];                         \
        float4 m3 = *(const float4*)&sMr[3][(c) * 4];                         \
        (A).x += DOT4(m0, v); (A).y += DOT4(m1, v);                           \
        (A).z += DOT4(m2, v); (A).w += DOT4(m3, v);                           \
    }

    float4 u0, u1;

    // t=0: i=q, row0, c=q
    u0 = S0[32 + q]; u1 = S1[32 + q];
    DOTS(q, v0, a0) DOTS(q, v1, a2)
    v0 = u0; v1 = u1;

    // t=1: i=32+q, row0
    u0 = S0[64 + q]; u1 = S1[64 + q];
    DOTS(32 + q, v0, a0) DOTS(32 + q, v1, a2)
    v0 = u0; v1 = u1;

    // t=2: i=64+q, row0 (max 95 < 100)
    u0 = S0[96 + q]; u1 = S1[96 + q];
    DOTS(64 + q, v0, a0) DOTS(64 + q, v1, a2)
    v0 = u0; v1 = u1;

    // t=3: i=96+q -> q<4: row0 c=96+q ; q>=4: row1 c=q-4
    u0 = S0[128 + q]; u1 = S1[128 + q];
    {
        int c3 = (q < 4) ? (96 + q) : (q - 4);
        float4 m0 = *(const float4*)&sMr[0][c3 * 4];
        float4 m1 = *(const float4*)&sMr[1][c3 * 4];
        float4 m2 = *(const float4*)&sMr[2][c3 * 4];
        float4 m3 = *(const float4*)&sMr[3][c3 * 4];
        float dx0 = DOT4(m0, v0), dy0 = DOT4(m1, v0), dz0 = DOT4(m2, v0), dw0 = DOT4(m3, v0);
        float dx1 = DOT4(m0, v1), dy1 = DOT4(m1, v1), dz1 = DOT4(m2, v1), dw1 = DOT4(m3, v1);
        if (q < 4) {
            a0.x += dx0; a0.y += dy0; a0.z += dz0; a0.w += dw0;
            a2.x += dx1; a2.y += dy1; a2.z += dz1; a2.w += dw1;
        } else {
            a1.x += dx0; a1.y += dy0; a1.z += dz0; a1.w += dw0;
            a3.x += dx1; a3.y += dy1; a3.z += dz1; a3.w += dw1;
        }
    }
    v0 = u0; v1 = u1;

    // t=4: i=128+q, row1, c=28+q
    u0 = S0[160 + q]; u1 = S1[160 + q];
    DOTS(28 + q, v0, a1) DOTS(28 + q, v1, a3)
    v0 = u0; v1 = u1;

    // t=5: i=160+q, row1, c=60+q ; prefetch tail (q<8 only, avoid OOB)
    if (q < 8) { u0 = S0[192 + q]; u1 = S1[192 + q]; }
    DOTS(60 + q, v0, a1) DOTS(60 + q, v1, a3)
    v0 = u0; v1 = u1;

    // t=6: i=192+q (q<8), row1, c=92+q
    if (q < 8) {
        DOTS(92 + q, v0, a1) DOTS(92 + q, v1, a3)
    }
    #undef DOTS

    // butterfly reduce across the 32-lane group (masks stay within the group)
    #define RED(f) f += __shfl_xor(f, 1); f += __shfl_xor(f, 2);  \
                   f += __shfl_xor(f, 4); f += __shfl_xor(f, 8);  \
                   f += __shfl_xor(f, 16);
    RED(a0.x) RED(a0.y) RED(a0.z) RED(a0.w)
    RED(a1.x) RED(a1.y) RED(a1.z) RED(a1.w)
    RED(a2.x) RED(a2.y) RED(a2.z) RED(a2.w)
    RED(a3.x) RED(a3.y) RED(a3.z) RED(a3.w)
    #undef RED

    // lane q<4 stores a_q at row 2*sp0+q: wave writes 8 consecutive float4
    // (128B contiguous, line-aligned).
    float4 o = a0;
    if (q == 1) o = a1;
    if (q == 2) o = a2;
    if (q == 3) o = a3;
    if (q < 4)
        out4[2 * sp0 + q] = o;
}

extern "C" void kernel_launch(void* const* d_in, const int* in_sizes, int n_in,
                              void* d_out, int out_size, void* d_ws, size_t ws_size,
                              hipStream_t stream) {
    const float4* T4 = (const float4*)d_in[0];
    const float*  Bo = (const float*)d_in[1];
    const float*  Bi = (const float*)d_in[2];
    const float*  W  = (const float*)d_in[3];
    // d_in[4] = K_mats (folded into analytic boost formula)

    float4* out4 = (float4*)d_out;

    int blocks = BATCH / 32;   // 32 rows = 16 super-rows per block
    lorentz_pair_kernel<<<blocks, 256, 0, stream>>>(T4, Bo, Bi, W, out4);
}

// Round 8
// 80.496 us; speedup vs baseline: 2.1289x; 1.0147x over previous
//
#include <hip/hip_runtime.h>
#include <math.h>

#define BATCH   262144
#define CLUSTER 100
#define TILES   4          // 64-row tiles per block; M built once per block

// Analytic Lorentz boost matrix B = I - (g*mag)*nK + (g-1)*nK^2:
//   B[0][0]     = g
//   B[0][j+1]   = B[j+1][0] = -(g*mag)*n_j
//   B[i+1][j+1] = delta_ij + (g-1)*n_i*n_j
__device__ inline void boost_mat(float bx, float by, float bz, float B[4][4]) {
    float m2  = bx * bx + by * by + bz * bz;
    float mag = sqrtf(m2);
    float nx = bx / mag, ny = by / mag, nz = bz / mag;
    float g  = 1.0f / sqrtf(1.0f - mag * mag);
    float gm = g * mag;
    float gm1 = g - 1.0f;
    float n[3] = {nx, ny, nz};
    B[0][0] = 1.0f + gm1 * (nx * nx + ny * ny + nz * nz);
    for (int j = 0; j < 3; ++j) {
        B[0][j + 1] = -gm * n[j];
        B[j + 1][0] = -gm * n[j];
    }
    for (int i = 0; i < 3; ++i)
        for (int j = 0; j < 3; ++j)
            B[i + 1][j + 1] = ((i == j) ? 1.0f : 0.0f) + gm1 * n[i] * n[j];
}

#define DOT4(mm, vv) ((mm).x*(vv).x + (mm).y*(vv).y + (mm).z*(vv).z + (mm).w*(vv).w)

// out[b][a] = sum_c sum_d M[c][a][d] * T[b][c][d],  M_c = BiM @ (W_c * BoM_c)
//
// R2-proven inner structure: 8-lane group, lane q handles clusters c = 8t+q
// (full 128B line per row per load instr), group owns rows base+g, base+g+8.
// NEW: each block processes TILES=4 consecutive 64-row tiles with ONE M-build
// and no inter-tile barrier -> the global-load stream never drains between
// tiles; per-CU pipeline fill/drain events drop 16x -> 4x (concurrent).
// M is SoA (sMr[a][c*4+d]): ds_read_b128 start bank = (16a+4q)%32, conflict-free.
__global__ __launch_bounds__(256) void lorentz_multitile_kernel(
        const float4* __restrict__ T4,
        const float*  __restrict__ Bo,
        const float*  __restrict__ Bi,
        const float*  __restrict__ W,
        float4* __restrict__ out4) {
    __shared__ float sMr[4][CLUSTER * 4];   // 6.4 KB

    int tid  = threadIdx.x;
    int w    = tid >> 6;
    int lane = tid & 63;
    int q = lane & 7;       // position in 8-lane group
    int g = lane >> 3;      // group 0..7

    // build all 100 M_c matrices once per block
    if (tid < CLUSTER) {
        float BiM[4][4], BoM[4][4];
        boost_mat(Bi[0], Bi[1], Bi[2], BiM);
        boost_mat(Bo[tid * 3 + 0], Bo[tid * 3 + 1], Bo[tid * 3 + 2], BoM);
        float wt = W[tid];
        for (int a = 0; a < 4; ++a)
            for (int d = 0; d < 4; ++d) {
                float s = 0.0f;
                for (int e = 0; e < 4; ++e)
                    s += BiM[a][e] * (wt * BoM[e][d]);
                sMr[a][tid * 4 + d] = s;
            }
    }
    __syncthreads();

    long long blockRow = (long long)blockIdx.x * (64 * TILES);

    #pragma unroll 1
    for (int tile = 0; tile < TILES; ++tile) {
        long long base = blockRow + tile * 64 + w * 16;
        const float4* P0 = T4 + (base + g)     * CLUSTER;
        const float4* P1 = T4 + (base + g + 8) * CLUSTER;

        float4 a0 = {0.f, 0.f, 0.f, 0.f};
        float4 a1 = a0;

        #pragma unroll 4
        for (int t = 0; t < 12; ++t) {
            int c = 8 * t + q;
            float4 v0 = P0[c];
            float4 v1 = P1[c];
            float4 m0 = *(const float4*)&sMr[0][c * 4];
            float4 m1 = *(const float4*)&sMr[1][c * 4];
            float4 m2 = *(const float4*)&sMr[2][c * 4];
            float4 m3 = *(const float4*)&sMr[3][c * 4];
            a0.x += DOT4(m0, v0); a0.y += DOT4(m1, v0); a0.z += DOT4(m2, v0); a0.w += DOT4(m3, v0);
            a1.x += DOT4(m0, v1); a1.y += DOT4(m1, v1); a1.z += DOT4(m2, v1); a1.w += DOT4(m3, v1);
        }
        if (q < 4) {                       // tail clusters 96..99
            int c = 96 + q;
            float4 v0 = P0[c];
            float4 v1 = P1[c];
            float4 m0 = *(const float4*)&sMr[0][c * 4];
            float4 m1 = *(const float4*)&sMr[1][c * 4];
            float4 m2 = *(const float4*)&sMr[2][c * 4];
            float4 m3 = *(const float4*)&sMr[3][c * 4];
            a0.x += DOT4(m0, v0); a0.y += DOT4(m1, v0); a0.z += DOT4(m2, v0); a0.w += DOT4(m3, v0);
            a1.x += DOT4(m0, v1); a1.y += DOT4(m1, v1); a1.z += DOT4(m2, v1); a1.w += DOT4(m3, v1);
        }

        // butterfly reduce across the 8-lane group
        #define RED(f) f += __shfl_xor(f, 1); f += __shfl_xor(f, 2); f += __shfl_xor(f, 4);
        RED(a0.x) RED(a0.y) RED(a0.z) RED(a0.w)
        RED(a1.x) RED(a1.y) RED(a1.z) RED(a1.w)
        #undef RED

        // wave writes 16 consecutive rows (256B contiguous)
        if (q == 0) out4[base + g]     = a0;
        if (q == 1) out4[base + g + 8] = a1;
    }
}

extern "C" void kernel_launch(void* const* d_in, const int* in_sizes, int n_in,
                              void* d_out, int out_size, void* d_ws, size_t ws_size,
                              hipStream_t stream) {
    const float4* T4 = (const float4*)d_in[0];
    const float*  Bo = (const float*)d_in[1];
    const float*  Bi = (const float*)d_in[2];
    const float*  W  = (const float*)d_in[3];
    // d_in[4] = K_mats (folded into analytic boost formula)

    float4* out4 = (float4*)d_out;

    int blocks = BATCH / (64 * TILES);   // 1024 blocks, 256 rows each
    lorentz_multitile_kernel<<<blocks, 256, 0, stream>>>(T4, Bo, Bi, W, out4);
}